// Round 2
// baseline (178.515 us; speedup 1.0000x reference)
//
#include <hip/hip_runtime.h>

// ExpandMask: zero-stuff stride-2 upsample + width-5 ones conv + (>0.5).
// Row-independent (B=64, C=1, L=262144). For input element i of a row:
//   out[2i]   = x[i-1] + x[i] + x[i+1]   (missing neighbors -> 0)
//   out[2i+1] = x[i]   + x[i+1]
// Output dtype is bool -> harness reads it as int32 (round-1 absmax was
// exactly bits(1.0f)-1). Store int 0/1.
// Memory-bound: 67 MB read + 134 MB write ~= 33 us floor at 6 TB/s.

#define ROW_LEN 262144           // L
#define VEC_PER_ROW (ROW_LEN/4)  // 65536 -> shift/mask for row split

__global__ __launch_bounds__(256)
void ExpandMask_kernel(const float* __restrict__ x, int* __restrict__ out) {
    const long long t = (long long)blockIdx.x * blockDim.x + threadIdx.x;
    const int row = (int)(t >> 16);        // t / 65536
    const int v   = (int)(t & 65535);      // vector index within row

    const float* xr = x + (long long)row * ROW_LEN;
    const float4 a = *(const float4*)(xr + (size_t)v * 4);

    // Halo scalars (cache hits from neighboring lanes' float4 lines)
    const float xm1 = (v == 0)               ? 0.0f : xr[(size_t)v * 4 - 1];
    const float xp4 = (v == VEC_PER_ROW - 1) ? 0.0f : xr[(size_t)v * 4 + 4];

    int4 o0, o1;
    o0.x = (xm1 + a.x + a.y) > 0.5f ? 1 : 0;  // y[2p0]
    o0.y = (a.x + a.y)       > 0.5f ? 1 : 0;  // y[2p0+1]
    o0.z = (a.x + a.y + a.z) > 0.5f ? 1 : 0;  // y[2p1]
    o0.w = (a.y + a.z)       > 0.5f ? 1 : 0;  // y[2p1+1]
    o1.x = (a.y + a.z + a.w) > 0.5f ? 1 : 0;  // y[2p2]
    o1.y = (a.z + a.w)       > 0.5f ? 1 : 0;  // y[2p2+1]
    o1.z = (a.z + a.w + xp4) > 0.5f ? 1 : 0;  // y[2p3]
    o1.w = (a.w + xp4)       > 0.5f ? 1 : 0;  // y[2p3+1]

    int4* op = (int4*)(out + (long long)row * (2 * ROW_LEN) + (size_t)v * 8);
    op[0] = o0;
    op[1] = o1;
}

extern "C" void kernel_launch(void* const* d_in, const int* in_sizes, int n_in,
                              void* d_out, int out_size, void* d_ws, size_t ws_size,
                              hipStream_t stream) {
    const float* x = (const float*)d_in[0];
    int* out = (int*)d_out;

    // total threads = B * L / 4 = 64 * 262144 / 4 = 4,194,304
    const long long total = 4194304LL;
    const int block = 256;
    const int grid = (int)(total / block);  // 16384
    ExpandMask_kernel<<<grid, block, 0, stream>>>(x, out);
}